// Round 1
// baseline (1455.182 us; speedup 1.0000x reference)
//
#include <hip/hip_runtime.h>

// ---------------------------------------------------------------------------
// DimNet: two collapsed 2D convs + pixel shuffle.
//   P   = padded input  (2, 25, 104, 104), 0.5 border, pic in [4:100)
//   BUF = relu(conv2a)  (2, 180, 100, 100), g = mc*9 + u*3 + v
//   out = pixelshuffle( (conv1(P)+b1 + relu(conv2b(BUF)+b2b)) / 2 )
// Weight flattening:
//   w1 : oc*2025 + c*81 + dy*9 + dx          (c = a1*5+a2)
//   w2a: mc*225 + ch9*25 + dy*5 + dx         (ch9 = da1*3+da2)
//   w2b: oc*4500 + g*25 + dy*5 + dx          (g = mc*9+u*3+v)
// fp32 baseline, compute-bound on VALU. ws: P then BUF (16.6 MB total).
// ---------------------------------------------------------------------------

#define NB 2
#define NCH 25
#define PH 104
#define PW 104
#define BUF_CH 180
#define BH 100
#define BW 100
#define OH 96
#define OW 96
#define LDSW 44   // padded LDS row stride (floats): multiple of 4 for float4

__global__ __launch_bounds__(256) void pad_kernel(const float* __restrict__ pic,
                                                  float* __restrict__ P) {
    int idx = blockIdx.x * 256 + threadIdx.x;
    const int total = NB * NCH * PH * PW;
    if (idx >= total) return;
    int x  = idx % PW;
    int y  = (idx / PW) % PH;
    int bc = idx / (PW * PH);
    float v = 0.5f;
    if (y >= 4 && y < 100 && x >= 4 && x < 100)
        v = pic[bc * (OH * OW) + (y - 4) * OW + (x - 4)];
    P[idx] = v;
}

// block: fixed (b, uv); 16x16 pixel tile; all 20 mc (4 groups x 5 mc).
// thread: 2x2 pixels x 5 mc accumulators.
__global__ __launch_bounds__(256) void conv2a_kernel(const float* __restrict__ P,
                                                     const float* __restrict__ w2a,
                                                     const float* __restrict__ b2a,
                                                     float* __restrict__ BUF) {
    __shared__ float sIn[9 * 20 * 21];   // [ch9][20 rows][21 cols padded]
    __shared__ float sW[20 * 225];
    const int b   = blockIdx.z;
    const int uv  = blockIdx.y;
    const int u   = uv / 3, v = uv % 3;
    const int tx0 = (blockIdx.x % 7) * 16;
    const int ty0 = (blockIdx.x / 7) * 16;
    const int tid = threadIdx.x;

    for (int i = tid; i < 20 * 225; i += 256) sW[i] = w2a[i];
    for (int i = tid; i < 9 * 20 * 20; i += 256) {
        int ch9 = i / 400;
        int r   = (i / 20) % 20;
        int cl  = i % 20;
        int c   = (u + ch9 / 3) * 5 + (v + ch9 % 3);
        int gy  = min(ty0 + r, PH - 1);   // clamp: clamped rows feed only discarded outputs
        int gx  = min(tx0 + cl, PW - 1);
        sIn[ch9 * 420 + r * 21 + cl] = P[((b * NCH + c) * PH + gy) * PW + gx];
    }
    __syncthreads();

    const int mcg = tid >> 6;       // 0..3 -> mc group of 5
    const int pid = tid & 63;
    const int px  = (pid & 7) * 2;  // 0..14
    const int py  = (pid >> 3) * 2; // 0..14

    float acc[5][2][2];
#pragma unroll
    for (int m = 0; m < 5; m++)
#pragma unroll
        for (int r = 0; r < 2; r++)
#pragma unroll
            for (int c = 0; c < 2; c++) acc[m][r][c] = 0.f;

    for (int ch9 = 0; ch9 < 9; ++ch9) {
        const float* in = &sIn[ch9 * 420];
#pragma unroll
        for (int dy = 0; dy < 5; ++dy) {
            float ra[6], rb[6];
#pragma unroll
            for (int k = 0; k < 6; k++) {
                ra[k] = in[(py + dy) * 21 + px + k];
                rb[k] = in[(py + 1 + dy) * 21 + px + k];
            }
#pragma unroll
            for (int dx = 0; dx < 5; ++dx) {
#pragma unroll
                for (int m = 0; m < 5; m++) {
                    float w = sW[(mcg * 5 + m) * 225 + ch9 * 25 + dy * 5 + dx];
                    acc[m][0][0] += ra[dx] * w;
                    acc[m][0][1] += ra[dx + 1] * w;
                    acc[m][1][0] += rb[dx] * w;
                    acc[m][1][1] += rb[dx + 1] * w;
                }
            }
        }
    }

#pragma unroll
    for (int m = 0; m < 5; m++) {
        int mc = mcg * 5 + m;
        float bias = b2a[mc];
        int g = mc * 9 + uv;
#pragma unroll
        for (int r = 0; r < 2; r++) {
            int y = ty0 + py + r;
            if (y >= BH) continue;
#pragma unroll
            for (int c = 0; c < 2; c++) {
                int x = tx0 + px + c;
                if (x >= BW) continue;
                BUF[((b * BUF_CH + g) * BH + y) * BW + x] = fmaxf(acc[m][r][c] + bias, 0.f);
            }
        }
    }
}

// block: 16 oc x (32w x 16h) pixels. thread: 4 oc x (4w x 2h) = 32 acc.
// Phase A: p2 = conv(BUF, w2b) [180ch, 5x5]; relu(+b2b);
// Phase B: += conv(P, w1) [25ch, 9x9]; write (acc+b1)*0.5 pixel-shuffled.
__global__ __launch_bounds__(256) void fused_kernel(const float* __restrict__ P,
                                                    const float* __restrict__ BUF,
                                                    const float* __restrict__ w1,
                                                    const float* __restrict__ b1,
                                                    const float* __restrict__ w2b,
                                                    const float* __restrict__ b2b,
                                                    float* __restrict__ out) {
    __shared__ float sIn[5 * 24 * LDSW];  // max(4*20, 5*24) rows x 44
    __shared__ float sW[5 * 81 * 16];     // [ch][tap][16 oc]
    const int b     = blockIdx.z;
    const int ocblk = blockIdx.y;           // 0..24 -> oc [16*ocblk, +16)
    const int tx0   = (blockIdx.x % 3) * 32;
    const int ty0   = (blockIdx.x / 3) * 16;
    const int tid   = threadIdx.x;
    const int ocg   = tid >> 6;             // 0..3 (also r1 of pixel shuffle)
    const int pid   = tid & 63;
    const int px    = (pid & 7) * 4;        // 0..28
    const int py    = (pid >> 3) * 2;       // 0..14

    float acc[4][2][4];
#pragma unroll
    for (int o = 0; o < 4; o++)
#pragma unroll
        for (int r = 0; r < 2; r++)
#pragma unroll
            for (int c = 0; c < 4; c++) acc[o][r][c] = 0.f;

    // ---------------- Phase A: conv2b over BUF ----------------
    for (int g0 = 0; g0 < BUF_CH; g0 += 4) {
        __syncthreads();
        for (int i = tid; i < 4 * 20 * 36; i += 256) {
            int ch  = i / 720;
            int rem = i - ch * 720;
            int r   = rem / 36, cl = rem - r * 36;
            sIn[(ch * 20 + r) * LDSW + cl] =
                BUF[((b * BUF_CH + g0 + ch) * BH + ty0 + r) * BW + tx0 + cl];
        }
        for (int i = tid; i < 4 * 25 * 16; i += 256) {
            int oc_l = i & 15;
            int tmp  = i >> 4;
            int t    = tmp % 25;
            int ch   = tmp / 25;
            sW[i] = w2b[(ocblk * 16 + oc_l) * 4500 + (g0 + ch) * 25 + t];
        }
        __syncthreads();
        for (int ch = 0; ch < 4; ++ch) {
            const float* in = &sIn[ch * 20 * LDSW];
            const float* wp = &sW[ch * 25 * 16];
#pragma unroll
            for (int dy = 0; dy < 5; ++dy) {
                const float4* pa = (const float4*)&in[(py + dy) * LDSW + px];
                const float4* pb = (const float4*)&in[(py + 1 + dy) * LDSW + px];
                float4 a0 = pa[0], a1 = pa[1];
                float4 q0 = pb[0], q1 = pb[1];
                float ra[8] = {a0.x, a0.y, a0.z, a0.w, a1.x, a1.y, a1.z, a1.w};
                float rb[8] = {q0.x, q0.y, q0.z, q0.w, q1.x, q1.y, q1.z, q1.w};
#pragma unroll
                for (int dx = 0; dx < 5; ++dx) {
                    float4 wv = *(const float4*)&wp[(dy * 5 + dx) * 16 + ocg * 4];
#pragma unroll
                    for (int c = 0; c < 4; c++) {
                        acc[0][0][c] += ra[dx + c] * wv.x;
                        acc[1][0][c] += ra[dx + c] * wv.y;
                        acc[2][0][c] += ra[dx + c] * wv.z;
                        acc[3][0][c] += ra[dx + c] * wv.w;
                        acc[0][1][c] += rb[dx + c] * wv.x;
                        acc[1][1][c] += rb[dx + c] * wv.y;
                        acc[2][1][c] += rb[dx + c] * wv.z;
                        acc[3][1][c] += rb[dx + c] * wv.w;
                    }
                }
            }
        }
    }

    // p2 = relu(acc + b2b)
    {
        const int oc_base = ocblk * 16 + ocg * 4;
        float4 bb = *(const float4*)&b2b[oc_base];
#pragma unroll
        for (int r = 0; r < 2; r++)
#pragma unroll
            for (int c = 0; c < 4; c++) {
                acc[0][r][c] = fmaxf(acc[0][r][c] + bb.x, 0.f);
                acc[1][r][c] = fmaxf(acc[1][r][c] + bb.y, 0.f);
                acc[2][r][c] = fmaxf(acc[2][r][c] + bb.z, 0.f);
                acc[3][r][c] = fmaxf(acc[3][r][c] + bb.w, 0.f);
            }
    }

    // ---------------- Phase B: conv1 over P ----------------
    for (int c0 = 0; c0 < NCH; c0 += 5) {
        __syncthreads();
        for (int i = tid; i < 5 * 24 * 40; i += 256) {
            int ch  = i / 960;
            int rem = i - ch * 960;
            int r   = rem / 40, cl = rem - r * 40;
            sIn[(ch * 24 + r) * LDSW + cl] =
                P[((b * NCH + c0 + ch) * PH + ty0 + r) * PW + tx0 + cl];
        }
        for (int i = tid; i < 5 * 81 * 16; i += 256) {
            int oc_l = i & 15;
            int tmp  = i >> 4;
            int t    = tmp % 81;
            int ch   = tmp / 81;
            sW[i] = w1[(ocblk * 16 + oc_l) * 2025 + (c0 + ch) * 81 + t];
        }
        __syncthreads();
        for (int ch = 0; ch < 5; ++ch) {
            const float* in = &sIn[ch * 24 * LDSW];
            const float* wp = &sW[ch * 81 * 16];
#pragma unroll
            for (int dy = 0; dy < 9; ++dy) {
                const float4* pa = (const float4*)&in[(py + dy) * LDSW + px];
                const float4* pb = (const float4*)&in[(py + 1 + dy) * LDSW + px];
                float4 a0 = pa[0], a1 = pa[1], a2 = pa[2];
                float4 q0 = pb[0], q1 = pb[1], q2 = pb[2];
                float ra[12] = {a0.x, a0.y, a0.z, a0.w, a1.x, a1.y,
                                a1.z, a1.w, a2.x, a2.y, a2.z, a2.w};
                float rb[12] = {q0.x, q0.y, q0.z, q0.w, q1.x, q1.y,
                                q1.z, q1.w, q2.x, q2.y, q2.z, q2.w};
#pragma unroll
                for (int dx = 0; dx < 9; ++dx) {
                    float4 wv = *(const float4*)&wp[(dy * 9 + dx) * 16 + ocg * 4];
#pragma unroll
                    for (int c = 0; c < 4; c++) {
                        acc[0][0][c] += ra[dx + c] * wv.x;
                        acc[1][0][c] += ra[dx + c] * wv.y;
                        acc[2][0][c] += ra[dx + c] * wv.z;
                        acc[3][0][c] += ra[dx + c] * wv.w;
                        acc[0][1][c] += rb[dx + c] * wv.x;
                        acc[1][1][c] += rb[dx + c] * wv.y;
                        acc[2][1][c] += rb[dx + c] * wv.z;
                        acc[3][1][c] += rb[dx + c] * wv.w;
                    }
                }
            }
        }
    }

    // epilogue: out = (p1 + p2)/2 with pixel shuffle.
    // oc = ocblk*16 + ocg*4 + o -> c25=ocblk, r1=ocg, r2=o.
    const int oc_base = ocblk * 16 + ocg * 4;
    float4 bv = *(const float4*)&b1[oc_base];
#pragma unroll
    for (int r = 0; r < 2; r++) {
        int y = ty0 + py + r;
#pragma unroll
        for (int c = 0; c < 4; c++) {
            int x = tx0 + px + c;
            float4 o4;
            o4.x = (acc[0][r][c] + bv.x) * 0.5f;
            o4.y = (acc[1][r][c] + bv.y) * 0.5f;
            o4.z = (acc[2][r][c] + bv.z) * 0.5f;
            o4.w = (acc[3][r][c] + bv.w) * 0.5f;
            size_t oidx = ((size_t)((b * 25 + ocblk) * 384 + y * 4 + ocg)) * 384 + x * 4;
            *(float4*)&out[oidx] = o4;
        }
    }
}

extern "C" void kernel_launch(void* const* d_in, const int* in_sizes, int n_in,
                              void* d_out, int out_size, void* d_ws, size_t ws_size,
                              hipStream_t stream) {
    const float* pic = (const float*)d_in[0];
    const float* w1  = (const float*)d_in[1];
    const float* b1  = (const float*)d_in[2];
    const float* w2a = (const float*)d_in[3];
    const float* b2a = (const float*)d_in[4];
    const float* w2b = (const float*)d_in[5];
    const float* b2b = (const float*)d_in[6];
    float* out = (float*)d_out;

    float* P   = (float*)d_ws;                       // 2*25*104*104 = 540800 f32
    float* BUF = P + (size_t)NB * NCH * PH * PW;     // 2*180*100*100 = 3.6M f32

    const int padN = NB * NCH * PH * PW;
    pad_kernel<<<(padN + 255) / 256, 256, 0, stream>>>(pic, P);
    conv2a_kernel<<<dim3(49, 9, NB), 256, 0, stream>>>(P, w2a, b2a, BUF);
    fused_kernel<<<dim3(18, 25, NB), 256, 0, stream>>>(P, BUF, w1, b1, w2b, b2b, out);
}

// Round 2
// 279.365 us; speedup vs baseline: 5.2089x; 5.2089x over previous
//
#include <hip/hip_runtime.h>
#include <hip/hip_bf16.h>

// ---------------------------------------------------------------------------
// DimNet via bf16 MFMA implicit GEMM (tap-loop rank-C update).
//   Pn  = padded input, NHWC bf16  [2][104][104][32]   (c<25 real, pad 0)
//   Bn  = relu(conv2a), NHWC bf16  [2][100][100][192]  (g<180 real, pad 0)
//   Wa  = w2b transposed [tap25][oc448][c192] bf16 (zero-padded)
//   Wb1 = w1  transposed [tap81][oc448][c32]  bf16 (zero-padded)
//   out = pixelshuffle( (conv1+b1 + relu(conv2b+b2b)) / 2 )
// conv_mfma: block = 256 pix x 64 oc, 4 waves of 64pix x 64oc,
//   mfma_f32_16x16x32_bf16, LDS chunk-XOR swizzle (2-way max, free).
// ---------------------------------------------------------------------------

typedef __attribute__((ext_vector_type(8))) unsigned short ushort8;
typedef __attribute__((ext_vector_type(8))) __bf16 bf16x8;
typedef __attribute__((ext_vector_type(4))) float f32x4;

#define NB 2
#define OH 96
#define OW 96

static __device__ __forceinline__ unsigned short f2bf(float f) {
    __hip_bfloat16 h = __float2bfloat16(f);
    return *reinterpret_cast<unsigned short*>(&h);
}
static __device__ __forceinline__ float bf2f(unsigned short u) {
    unsigned int v = ((unsigned int)u) << 16;
    return __uint_as_float(v);
}

// ---------------- pad + NHWC transpose of pic ----------------
__global__ __launch_bounds__(256) void pad_nhwc_kernel(const float* __restrict__ pic,
                                                       unsigned short* __restrict__ Pn) {
    int idx = blockIdx.x * 256 + threadIdx.x;
    if (idx >= NB * 104 * 104) return;
    int x = idx % 104;
    int y = (idx / 104) % 104;
    int b = idx / (104 * 104);
    unsigned short vals[32];
    bool inter = (y >= 4 && y < 100 && x >= 4 && x < 100);
#pragma unroll
    for (int c = 0; c < 25; ++c) {
        float v = inter ? pic[((b * 25 + c) * 96 + (y - 4)) * 96 + (x - 4)] : 0.5f;
        vals[c] = f2bf(v);
    }
#pragma unroll
    for (int c = 25; c < 32; ++c) vals[c] = 0;
    ushort8* dst = (ushort8*)(Pn + idx * 32);
#pragma unroll
    for (int j = 0; j < 4; ++j) dst[j] = *(ushort8*)&vals[j * 8];
}

// ---------------- weight prep: transpose + bf16 + pad ----------------
#define NWA (25 * 448 * 192)
#define NWB (81 * 448 * 32)
__global__ __launch_bounds__(256) void prep_w_kernel(const float* __restrict__ w2b,
                                                     const float* __restrict__ w1,
                                                     unsigned short* __restrict__ Wa,
                                                     unsigned short* __restrict__ Wb1) {
    int idx = blockIdx.x * 256 + threadIdx.x;
    if (idx < NWA) {
        int c   = idx % 192;
        int oc  = (idx / 192) % 448;
        int tap = idx / (192 * 448);
        float v = (oc < 400 && c < 180) ? w2b[oc * 4500 + c * 25 + tap] : 0.f;
        Wa[idx] = f2bf(v);
    } else {
        int k = idx - NWA;
        if (k >= NWB) return;
        int c   = k % 32;
        int oc  = (k / 32) % 448;
        int tap = k / (32 * 448);
        float v = (oc < 400 && c < 25) ? w1[oc * 2025 + c * 81 + tap] : 0.f;
        Wb1[k] = f2bf(v);
    }
}

// ---------------- conv2a (fp32 VALU, small: 1.6 GFLOP) ----------------
// block: fixed (b, uv); 16x16 pixel tile; 20 mc (4 groups x 5).
__global__ __launch_bounds__(256) void conv2a_kernel(const unsigned short* __restrict__ Pn,
                                                     const float* __restrict__ w2a,
                                                     const float* __restrict__ b2a,
                                                     unsigned short* __restrict__ Bn) {
    __shared__ float sIn[9 * 20 * 21];
    __shared__ float sW[20 * 225];
    const int b   = blockIdx.z;
    const int uv  = blockIdx.y;
    const int u   = uv / 3, v = uv % 3;
    const int tx0 = (blockIdx.x % 7) * 16;
    const int ty0 = (blockIdx.x / 7) * 16;
    const int tid = threadIdx.x;

    for (int i = tid; i < 20 * 225; i += 256) sW[i] = w2a[i];
    for (int i = tid; i < 9 * 20 * 20; i += 256) {
        int ch9 = i / 400;
        int r   = (i / 20) % 20;
        int cl  = i % 20;
        int c   = (u + ch9 / 3) * 5 + (v + ch9 % 3);
        int gy  = min(ty0 + r, 103);
        int gx  = min(tx0 + cl, 103);
        sIn[ch9 * 420 + r * 21 + cl] = bf2f(Pn[((b * 104 + gy) * 104 + gx) * 32 + c]);
    }
    __syncthreads();

    const int mcg = tid >> 6;
    const int pid = tid & 63;
    const int px  = (pid & 7) * 2;
    const int py  = (pid >> 3) * 2;

    float acc[5][2][2];
#pragma unroll
    for (int m = 0; m < 5; m++)
#pragma unroll
        for (int r = 0; r < 2; r++)
#pragma unroll
            for (int c = 0; c < 2; c++) acc[m][r][c] = 0.f;

    for (int ch9 = 0; ch9 < 9; ++ch9) {
        const float* in = &sIn[ch9 * 420];
#pragma unroll
        for (int dy = 0; dy < 5; ++dy) {
            float ra[6], rb[6];
#pragma unroll
            for (int k = 0; k < 6; k++) {
                ra[k] = in[(py + dy) * 21 + px + k];
                rb[k] = in[(py + 1 + dy) * 21 + px + k];
            }
#pragma unroll
            for (int dx = 0; dx < 5; ++dx) {
#pragma unroll
                for (int m = 0; m < 5; m++) {
                    float w = sW[(mcg * 5 + m) * 225 + ch9 * 25 + dy * 5 + dx];
                    acc[m][0][0] += ra[dx] * w;
                    acc[m][0][1] += ra[dx + 1] * w;
                    acc[m][1][0] += rb[dx] * w;
                    acc[m][1][1] += rb[dx + 1] * w;
                }
            }
        }
    }

#pragma unroll
    for (int m = 0; m < 5; m++) {
        int mc = mcg * 5 + m;
        float bias = b2a[mc];
        int g = mc * 9 + uv;
#pragma unroll
        for (int r = 0; r < 2; r++) {
            int y = ty0 + py + r;
            if (y >= 100) continue;
#pragma unroll
            for (int c = 0; c < 2; c++) {
                int x = tx0 + px + c;
                if (x >= 100) continue;
                Bn[((b * 100 + y) * 100 + x) * 192 + g] = f2bf(fmaxf(acc[m][r][c] + bias, 0.f));
            }
        }
    }
}

// ---------------- the big one: both convs via MFMA ----------------
__global__ __launch_bounds__(256) void conv_mfma_kernel(
    const unsigned short* __restrict__ Pn, const unsigned short* __restrict__ Bn,
    const unsigned short* __restrict__ Wa, const unsigned short* __restrict__ Wb1,
    const float* __restrict__ b1, const float* __restrict__ b2b,
    float* __restrict__ out) {
    __shared__ unsigned short sA[256 * 32];  // [pix][32k] chunk-XOR swizzled (16 KB)
    __shared__ unsigned short sB[64 * 32];   // [oc][32k]  chunk-XOR swizzled (4 KB)

    const int tid = threadIdx.x;
    const int ocB = blockIdx.y;  // 0..6 -> oc [64*ocB, +64), >=400 masked
    const int pb  = blockIdx.x;  // 0..71
    const int b   = pb / 36;
    const int t36 = pb % 36;
    const int ty0 = (t36 / 3) * 8;
    const int tx0 = (t36 % 3) * 32;

    // A staging: thread loads 4 x 16B (one per pixel quarter), chunk = tid&3
    const int ach = tid & 3;
    const int ap  = tid >> 2;
    const int wslot = ((ach ^ (ap & 3)) << 3);
    int aGlobA[4], aGlobP[4], aWr[4];
#pragma unroll
    for (int j = 0; j < 4; ++j) {
        int p = j * 64 + ap;
        int y = ty0 + (p >> 5), x = tx0 + (p & 31);
        aGlobA[j] = ((b * 100 + y) * 100 + x) * 192 + ach * 8;
        aGlobP[j] = ((b * 104 + y) * 104 + x) * 32 + ach * 8;
        aWr[j]    = p * 32 + wslot;
    }
    // B staging: thread (oc_l = tid>>2, chunk = tid&3)
    const int oc_l = tid >> 2, bj = tid & 3;
    const int ocg  = ocB * 64 + oc_l;
    const int wA0  = ocg * 192 + bj * 8;
    const int wB0  = ocg * 32 + bj * 8;
    const int bWr  = oc_l * 32 + ((bj ^ (oc_l & 3)) << 3);
    // fragment read offsets
    const int l = tid & 63, w = tid >> 6;
    const int lhi = l >> 4, l15 = l & 15;
    const int aRd = (w * 64 + l15) * 32 + ((lhi ^ (l15 & 3)) << 3);
    const int bRd = l15 * 32 + ((lhi ^ (l15 & 3)) << 3);

    f32x4 acc[4][4] = {};

    // -------- Phase A: conv2b over BUF (25 taps x 6 c-chunks) --------
    for (int tap = 0; tap < 25; ++tap) {
        const int dy = tap / 5, dx = tap % 5;
        const int tOff = (dy * 100 + dx) * 192;
        const unsigned short* wTap = Wa + tap * (448 * 192) + wA0;
        for (int cc = 0; cc < 6; ++cc) {
            const int c0 = cc * 32;
            ushort8 av[4];
#pragma unroll
            for (int j = 0; j < 4; ++j)
                av[j] = *(const ushort8*)(Bn + aGlobA[j] + tOff + c0);
            ushort8 bv = *(const ushort8*)(wTap + c0);
            __syncthreads();
#pragma unroll
            for (int j = 0; j < 4; ++j) *(ushort8*)&sA[aWr[j]] = av[j];
            *(ushort8*)&sB[bWr] = bv;
            __syncthreads();
            bf16x8 af[4], bfr[4];
#pragma unroll
            for (int m = 0; m < 4; ++m) af[m] = *(const bf16x8*)&sA[aRd + m * 512];
#pragma unroll
            for (int n = 0; n < 4; ++n) bfr[n] = *(const bf16x8*)&sB[bRd + n * 512];
#pragma unroll
            for (int m = 0; m < 4; ++m)
#pragma unroll
                for (int n = 0; n < 4; ++n)
                    acc[m][n] = __builtin_amdgcn_mfma_f32_16x16x32_bf16(
                        af[m], bfr[n], acc[m][n], 0, 0, 0);
        }
    }

    // -------- p2 = relu(acc + b2b) --------
    {
        float bb2[4];
#pragma unroll
        for (int n = 0; n < 4; ++n) {
            int oc = ocB * 64 + n * 16 + l15;
            bb2[n] = b2b[oc < 400 ? oc : 399];
        }
#pragma unroll
        for (int m = 0; m < 4; ++m)
#pragma unroll
            for (int n = 0; n < 4; ++n)
#pragma unroll
                for (int i = 0; i < 4; ++i)
                    acc[m][n][i] = fmaxf(acc[m][n][i] + bb2[n], 0.f);
    }

    // -------- Phase B: conv1 over P (81 taps x 1 c-chunk) --------
    for (int tap = 0; tap < 81; ++tap) {
        const int dy = tap / 9, dx = tap % 9;
        const int tOff = (dy * 104 + dx) * 32;
        ushort8 av[4];
#pragma unroll
        for (int j = 0; j < 4; ++j)
            av[j] = *(const ushort8*)(Pn + aGlobP[j] + tOff);
        ushort8 bv = *(const ushort8*)(Wb1 + tap * (448 * 32) + wB0);
        __syncthreads();
#pragma unroll
        for (int j = 0; j < 4; ++j) *(ushort8*)&sA[aWr[j]] = av[j];
        *(ushort8*)&sB[bWr] = bv;
        __syncthreads();
        bf16x8 af[4], bfr[4];
#pragma unroll
        for (int m = 0; m < 4; ++m) af[m] = *(const bf16x8*)&sA[aRd + m * 512];
#pragma unroll
        for (int n = 0; n < 4; ++n) bfr[n] = *(const bf16x8*)&sB[bRd + n * 512];
#pragma unroll
        for (int m = 0; m < 4; ++m)
#pragma unroll
            for (int n = 0; n < 4; ++n)
                acc[m][n] = __builtin_amdgcn_mfma_f32_16x16x32_bf16(
                    af[m], bfr[n], acc[m][n], 0, 0, 0);
    }

    // -------- epilogue: (acc + b1)/2, pixel-shuffled store --------
    // D frag: col = l&15 -> oc_local, row = lhi*4 + i -> pixel.
#pragma unroll
    for (int n = 0; n < 4; ++n) {
        int oc = ocB * 64 + n * 16 + l15;
        if (oc >= 400) continue;
        float bv = b1[oc];
        int c25 = oc >> 4, r1 = (oc >> 2) & 3, r2 = oc & 3;
#pragma unroll
        for (int m = 0; m < 4; ++m) {
#pragma unroll
            for (int i = 0; i < 4; ++i) {
                int p  = w * 64 + m * 16 + lhi * 4 + i;
                int py = ty0 + (p >> 5), px = tx0 + (p & 31);
                out[((b * 25 + c25) * 384 + py * 4 + r1) * 384 + px * 4 + r2] =
                    (acc[m][n][i] + bv) * 0.5f;
            }
        }
    }
}

extern "C" void kernel_launch(void* const* d_in, const int* in_sizes, int n_in,
                              void* d_out, int out_size, void* d_ws, size_t ws_size,
                              hipStream_t stream) {
    const float* pic = (const float*)d_in[0];
    const float* w1  = (const float*)d_in[1];
    const float* b1  = (const float*)d_in[2];
    const float* w2a = (const float*)d_in[3];
    const float* b2a = (const float*)d_in[4];
    const float* w2b = (const float*)d_in[5];
    const float* b2b = (const float*)d_in[6];
    float* out = (float*)d_out;

    char* ws = (char*)d_ws;
    unsigned short* Pn  = (unsigned short*)(ws);             // 692,224 el -> 1,384,448 B
    unsigned short* Bn  = (unsigned short*)(ws + 1384448);   // 3,840,000 el -> 7,680,000 B
    unsigned short* Wa  = (unsigned short*)(ws + 9064448);   // 2,150,400 el -> 4,300,800 B
    unsigned short* Wb1 = (unsigned short*)(ws + 13365248);  // 1,161,216 el -> 2,322,432 B
    // total 15,687,680 B (< 16.56 MB known available)

    pad_nhwc_kernel<<<(NB * 104 * 104 + 255) / 256, 256, 0, stream>>>(pic, Pn);
    prep_w_kernel<<<(NWA + NWB + 255) / 256, 256, 0, stream>>>(w2b, w1, Wa, Wb1);
    hipMemsetAsync(Bn, 0, 7680000, stream);  // zero pad channels g in [180,192)
    conv2a_kernel<<<dim3(49, 9, NB), 256, 0, stream>>>(Pn, w2a, b2a, Bn);
    conv_mfma_kernel<<<dim3(72, 7), 256, 0, stream>>>(Pn, Bn, Wa, Wb1, b1, b2b, out);
}

// Round 3
// 231.383 us; speedup vs baseline: 6.2891x; 1.2074x over previous
//
#include <hip/hip_runtime.h>
#include <hip/hip_bf16.h>

// ---------------------------------------------------------------------------
// DimNet via bf16 MFMA implicit GEMM, pipelined (global_load_lds + counted
// vmcnt, depth-2 prefetch, 4 LDS buffers, 1 barrier/step).
//   Pn  = padded input, NHWC bf16  [2][104][104][32]   (c<25 real, pad 0)
//   Pp  = padded input, planar bf16 [2][25][104][104]  (for conv2a; aliases Wa)
//   Bn  = relu(conv2a), NHWC bf16  [2][100][100][192]  (g' = uv*20+mc, pad 0)
//   Wa  = w2b transposed [tap25][oc448][c192] bf16 (c = g' relabel)
//   Wb1 = w1  transposed [tap81][oc448][c32]  bf16
// conv_mfma: 256 pix x 64 oc block, 4 waves (64x64 each), 231 K-steps of 32.
// ---------------------------------------------------------------------------

typedef __attribute__((ext_vector_type(8))) unsigned short ushort8;
typedef __attribute__((ext_vector_type(8))) __bf16 bf16x8;
typedef __attribute__((ext_vector_type(4))) float f32x4;

#define NB 2
#define NSTEP 231  // 150 phase-A (25 taps x 6 c-chunks) + 81 phase-B taps

static __device__ __forceinline__ unsigned short f2bf(float f) {
    __hip_bfloat16 h = __float2bfloat16(f);
    return *reinterpret_cast<unsigned short*>(&h);
}
static __device__ __forceinline__ float bf2f(unsigned short u) {
    unsigned int v = ((unsigned int)u) << 16;
    return __uint_as_float(v);
}

static __device__ __forceinline__ void gload16(const unsigned short* g, unsigned short* l) {
    __builtin_amdgcn_global_load_lds(
        (const __attribute__((address_space(1))) unsigned int*)(const void*)g,
        (__attribute__((address_space(3))) unsigned int*)(void*)l, 16, 0, 0);
}

// ---------------- pad: NHWC bf16 + planar bf16 ----------------
__global__ __launch_bounds__(256) void pad_kernel(const float* __restrict__ pic,
                                                  unsigned short* __restrict__ Pn,
                                                  unsigned short* __restrict__ Pp) {
    int idx = blockIdx.x * 256 + threadIdx.x;
    if (idx >= NB * 104 * 104) return;
    int x = idx % 104;
    int y = (idx / 104) % 104;
    int b = idx / (104 * 104);
    unsigned short vals[32];
    bool inter = (y >= 4 && y < 100 && x >= 4 && x < 100);
#pragma unroll
    for (int c = 0; c < 25; ++c) {
        float v = inter ? pic[((b * 25 + c) * 96 + (y - 4)) * 96 + (x - 4)] : 0.5f;
        vals[c] = f2bf(v);
        Pp[((b * 25 + c) * 104 + y) * 104 + x] = vals[c];
    }
#pragma unroll
    for (int c = 25; c < 32; ++c) vals[c] = 0;
    ushort8* dst = (ushort8*)(Pn + idx * 32);
#pragma unroll
    for (int j = 0; j < 4; ++j) dst[j] = *(ushort8*)&vals[j * 8];
}

// ---------------- weight prep ----------------
#define NWA (25 * 448 * 192)
#define NWB (81 * 448 * 32)
__global__ __launch_bounds__(256) void prep_w_kernel(const float* __restrict__ w2b,
                                                     const float* __restrict__ w1,
                                                     unsigned short* __restrict__ Wa,
                                                     unsigned short* __restrict__ Wb1) {
    int idx = blockIdx.x * 256 + threadIdx.x;
    if (idx < NWA) {
        int c   = idx % 192;
        int oc  = (idx / 192) % 448;
        int tap = idx / (192 * 448);
        float v = 0.f;
        if (oc < 400 && c < 180) {
            int mc = c % 20, uv = c / 20;              // g' = uv*20 + mc
            v = w2b[oc * 4500 + (mc * 9 + uv) * 25 + tap];
        }
        Wa[idx] = f2bf(v);
    } else {
        int k = idx - NWA;
        if (k >= NWB) return;
        int c   = k % 32;
        int oc  = (k / 32) % 448;
        int tap = k / (32 * 448);
        float v = (oc < 400 && c < 25) ? w1[oc * 2025 + c * 81 + tap] : 0.f;
        Wb1[k] = f2bf(v);
    }
}

// ---------------- conv2a (fp32 VALU, 1.6 GFLOP) ----------------
__global__ __launch_bounds__(256) void conv2a_kernel(const unsigned short* __restrict__ Pp,
                                                     const float* __restrict__ w2a,
                                                     const float* __restrict__ b2a,
                                                     unsigned short* __restrict__ Bn) {
    __shared__ float sIn[9 * 20 * 21];
    __shared__ float sW[20 * 225];
    const int b   = blockIdx.z;
    const int uv  = blockIdx.y;
    const int u   = uv / 3, v = uv % 3;
    const int tx0 = (blockIdx.x % 7) * 16;
    const int ty0 = (blockIdx.x / 7) * 16;
    const int tid = threadIdx.x;

    for (int i = tid; i < 20 * 225; i += 256) sW[i] = w2a[i];
    for (int i = tid; i < 9 * 20 * 20; i += 256) {
        int ch9 = i / 400;
        int r   = (i / 20) % 20;
        int cl  = i % 20;
        int c   = (u + ch9 / 3) * 5 + (v + ch9 % 3);
        int gy  = min(ty0 + r, 103);
        int gx  = min(tx0 + cl, 103);
        sIn[ch9 * 420 + r * 21 + cl] = bf2f(Pp[((b * 25 + c) * 104 + gy) * 104 + gx]);
    }
    __syncthreads();

    const int mcg = tid >> 6;
    const int pid = tid & 63;
    const int px  = (pid & 7) * 2;
    const int py  = (pid >> 3) * 2;

    float acc[5][2][2];
#pragma unroll
    for (int m = 0; m < 5; m++)
#pragma unroll
        for (int r = 0; r < 2; r++)
#pragma unroll
            for (int c = 0; c < 2; c++) acc[m][r][c] = 0.f;

    for (int ch9 = 0; ch9 < 9; ++ch9) {
        const float* in = &sIn[ch9 * 420];
#pragma unroll
        for (int dy = 0; dy < 5; ++dy) {
            float ra[6], rb[6];
#pragma unroll
            for (int k = 0; k < 6; k++) {
                ra[k] = in[(py + dy) * 21 + px + k];
                rb[k] = in[(py + 1 + dy) * 21 + px + k];
            }
#pragma unroll
            for (int dx = 0; dx < 5; ++dx) {
#pragma unroll
                for (int m = 0; m < 5; m++) {
                    float w = sW[(mcg * 5 + m) * 225 + ch9 * 25 + dy * 5 + dx];
                    acc[m][0][0] += ra[dx] * w;
                    acc[m][0][1] += ra[dx + 1] * w;
                    acc[m][1][0] += rb[dx] * w;
                    acc[m][1][1] += rb[dx + 1] * w;
                }
            }
        }
    }

#pragma unroll
    for (int m = 0; m < 5; m++) {
        int mc = mcg * 5 + m;
        float bias = b2a[mc];
        int gp = uv * 20 + mc;                        // g' layout
#pragma unroll
        for (int r = 0; r < 2; r++) {
            int y = ty0 + py + r;
            if (y >= 100) continue;
#pragma unroll
            for (int c = 0; c < 2; c++) {
                int x = tx0 + px + c;
                if (x >= 100) continue;
                Bn[((b * 100 + y) * 100 + x) * 192 + gp] = f2bf(fmaxf(acc[m][r][c] + bias, 0.f));
                if (uv == 0 && mcg == 3) {           // zero pad channels [180,192)
#pragma unroll
                    for (int z = 0; z < 12; ++z)
                        Bn[((b * 100 + y) * 100 + x) * 192 + 180 + z] = 0;
                }
            }
        }
    }
}

// ---------------- pipelined MFMA conv ----------------
__global__ __launch_bounds__(256) void conv_mfma_kernel(
    const unsigned short* __restrict__ Pn, const unsigned short* __restrict__ Bn,
    const unsigned short* __restrict__ Wa, const unsigned short* __restrict__ Wb1,
    const float* __restrict__ b1, const float* __restrict__ b2b,
    float* __restrict__ out) {
    __shared__ unsigned short sA[4][8192];  // 4 bufs x [256 pix][32k]  (64 KB)
    __shared__ unsigned short sB[4][2048];  // 4 bufs x [64 oc][32k]    (16 KB)

    const int tid = threadIdx.x;
    const int ocB = blockIdx.y;
    const int pb  = blockIdx.x;
    const int b   = pb / 36;
    const int t36 = pb % 36;
    const int ty0 = (t36 / 3) * 8;
    const int tx0 = (t36 % 3) * 32;

    const int l   = tid & 63, w = tid >> 6;
    const int l15 = l & 15, lhi = l >> 4;
    const int slot = ((lhi ^ ((l15 >> 1) & 3)) << 3);
    const int aRd = (w * 64 + l15) * 32 + slot;
    const int bRd = l15 * 32 + slot;
    const int qa  = (((l & 3) ^ ((l >> 3) & 3)) << 3);  // source quarter (ushorts)

    int aBaseA[4], aBaseP[4];
#pragma unroll
    for (int i = 0; i < 4; ++i) {
        int p = w * 64 + i * 16 + (l >> 2);
        int y = ty0 + (p >> 5), x = tx0 + (p & 31);
        aBaseA[i] = ((b * 100 + y) * 100 + x) * 192 + qa;
        aBaseP[i] = ((b * 104 + y) * 104 + x) * 32 + qa;
    }
    const int oc_l   = w * 16 + (l >> 2);
    const int bBaseA = (ocB * 64 + oc_l) * 192 + qa;
    const int bBaseB = (ocB * 64 + oc_l) * 32 + qa;

    // bias preload (before any staging: oldest vmem ops, retire first)
    float bb2[4], bb1[4];
#pragma unroll
    for (int n = 0; n < 4; ++n) {
        int oc = ocB * 64 + n * 16 + l15;
        int occ = oc < 400 ? oc : 399;
        bb2[n] = b2b[occ];
        bb1[n] = b1[occ];
    }

    f32x4 acc[4][4] = {};

    auto stage = [&](int t) {
        unsigned short* sAd = &sA[t & 3][w * 2048];
        unsigned short* sBd = &sB[t & 3][w * 512];
        if (t < 150) {
            int tap = t / 6, cc = t - tap * 6;
            int dy = tap / 5, dx = tap - dy * 5;
            const unsigned short* sa = Bn + (dy * 100 + dx) * 192 + cc * 32;
#pragma unroll
            for (int i = 0; i < 4; ++i) gload16(sa + aBaseA[i], sAd + i * 512);
            gload16(Wa + tap * (448 * 192) + cc * 32 + bBaseA, sBd);
        } else {
            int tap = t - 150;
            int dy = tap / 9, dx = tap - dy * 9;
            const unsigned short* sa = Pn + (dy * 104 + dx) * 32;
#pragma unroll
            for (int i = 0; i < 4; ++i) gload16(sa + aBaseP[i], sAd + i * 512);
            gload16(Wb1 + tap * (448 * 32) + bBaseB, sBd);
        }
    };

    auto compute = [&](int s) {
        const unsigned short* pa = &sA[s & 3][aRd];
        const unsigned short* pb = &sB[s & 3][bRd];
        bf16x8 af[4], bfv[4];
#pragma unroll
        for (int m = 0; m < 4; ++m) af[m] = *(const bf16x8*)(pa + m * 512);
#pragma unroll
        for (int n = 0; n < 4; ++n) bfv[n] = *(const bf16x8*)(pb + n * 512);
#pragma unroll
        for (int m = 0; m < 4; ++m)
#pragma unroll
            for (int n = 0; n < 4; ++n)
                acc[m][n] = __builtin_amdgcn_mfma_f32_16x16x32_bf16(af[m], bfv[n],
                                                                    acc[m][n], 0, 0, 0);
    };

#define STEP(S, VN)                                              \
    {                                                            \
        if ((S) + 2 < NSTEP) stage((S) + 2);                     \
        asm volatile("s_waitcnt vmcnt(" #VN ")" ::: "memory");   \
        asm volatile("s_barrier" ::: "memory");                  \
        compute(S);                                              \
    }

    stage(0);
    stage(1);
    for (int s = 0; s < 150; ++s) STEP(s, 10);

    // p2 = relu(p2 + b2b)
#pragma unroll
    for (int m = 0; m < 4; ++m)
#pragma unroll
        for (int n = 0; n < 4; ++n)
#pragma unroll
            for (int i = 0; i < 4; ++i)
                acc[m][n][i] = fmaxf(acc[m][n][i] + bb2[n], 0.f);

    for (int s = 150; s < 229; ++s) STEP(s, 10);
    STEP(229, 5);
    STEP(230, 0);
#undef STEP

    // epilogue: (p1+p2+b1)/2, pixel-shuffled
#pragma unroll
    for (int n = 0; n < 4; ++n) {
        int oc = ocB * 64 + n * 16 + l15;
        if (oc >= 400) continue;
        float bv = bb1[n];
        int c25 = oc >> 4, r1 = (oc >> 2) & 3, r2 = oc & 3;
#pragma unroll
        for (int m = 0; m < 4; ++m) {
#pragma unroll
            for (int i = 0; i < 4; ++i) {
                int p  = w * 64 + m * 16 + lhi * 4 + i;
                int py = ty0 + (p >> 5), px = tx0 + (p & 31);
                out[((b * 25 + c25) * 384 + py * 4 + r1) * 384 + px * 4 + r2] =
                    (acc[m][n][i] + bv) * 0.5f;
            }
        }
    }
}

extern "C" void kernel_launch(void* const* d_in, const int* in_sizes, int n_in,
                              void* d_out, int out_size, void* d_ws, size_t ws_size,
                              hipStream_t stream) {
    const float* pic = (const float*)d_in[0];
    const float* w1  = (const float*)d_in[1];
    const float* b1  = (const float*)d_in[2];
    const float* w2a = (const float*)d_in[3];
    const float* b2a = (const float*)d_in[4];
    const float* w2b = (const float*)d_in[5];
    const float* b2b = (const float*)d_in[6];
    float* out = (float*)d_out;

    char* ws = (char*)d_ws;
    unsigned short* Pn  = (unsigned short*)(ws);             // 1,384,448 B
    unsigned short* Bn  = (unsigned short*)(ws + 1384448);   // 7,680,000 B
    unsigned short* Wa  = (unsigned short*)(ws + 9064448);   // 4,300,800 B
    unsigned short* Wb1 = (unsigned short*)(ws + 13365248);  // 2,322,432 B
    unsigned short* Pp  = Wa;  // planar bf16 P aliases Wa (dead before prep_w)

    pad_kernel<<<(NB * 104 * 104 + 255) / 256, 256, 0, stream>>>(pic, Pn, Pp);
    conv2a_kernel<<<dim3(49, 9, NB), 256, 0, stream>>>(Pp, w2a, b2a, Bn);
    prep_w_kernel<<<(NWA + NWB + 255) / 256, 256, 0, stream>>>(w2b, w1, Wa, Wb1);
    conv_mfma_kernel<<<dim3(72, 7), 256, 0, stream>>>(Pn, Bn, Wa, Wb1, b1, b2b, out);
}